// Round 5
// baseline (78795.233 us; speedup 1.0000x reference)
//
#include <hip/hip_runtime.h>

// LSTM LM forward on gfx950.
// R15 = R10 protocol/geometry (128 worker WGs, 4 groups x 32 WGs x 16 batches,
// 1 h-slot/wave, wfrag[20], proven 2941us) + XCD-LOCAL L2 fast path for the
// H exchange, with unconditional agent-scope fallback.
// Evidence: R12 (ready-signal) and R13 (4x less poll traffic) both left
// L_eff ~5900cyc -> the wait is the raw MALL rendezvous latency of
// agent-scope exchange. Fix: keep each group's 32 WGs on ONE XCD and
// exchange through that XCD's L2 (sc0 loads bypass L1; plain stores are
// write-through to L2; intra-XCD L2 is CU-coherent).
// R14 (exception) post-mortem -> three fixes:
//  - No dynamic LDS / no 1-WG/CU forcing: 256 WGs x 256thr, 47KiB static;
//    cooperative co-residency + one-time grid barrier (agent atomics).
//  - Role assignment deadlock-proof: WG claims slot in group=XCC_ID (XCDs
//    0-3); after barrier, deficits are filled deterministically by spill
//    WGs; group uses LOCAL mode iff fully claimed by its own XCD, else
//    agent mode (R10 path).
//  - Local poll = ONE asm block (8x global_load_dwordx4 sc0 + vmcnt inside)
//    -> no deferred-wait regalloc hazard. Local region laid out per-thread
//    contiguous (128B/thread) so one base + imm offsets cover it.
//  - Producers dual-publish (plain store -> local region; agent atomic ->
//    R10 region). Sticky 8192-round timeout drops a thread to the agent
//    path forever -> worst case ~ R10 + 1ms, no hang.
// Carried from R10: tagged u64 {step, 2xbf16}, reload-all resweep,
// Hs parity dbuf + Xs triple-buf, one barrier/step, deferred Y flush via
// yred parity LDS + reduce_y, 2-way split accumulator, folded head Y.

typedef short bf16x8 __attribute__((ext_vector_type(8)));
typedef float f32x4  __attribute__((ext_vector_type(4)));
typedef unsigned u32x4 __attribute__((ext_vector_type(4)));
typedef unsigned short ushort_t;
typedef unsigned long long u64;

#define S_LEN 1024
#define NB    64
#define NH    512
#define NE    128
#define NGRP  4
#define NWPG  32              // worker WGs per group
#define NWGT  256             // launched WGs (128 get slots, rest exit)

// workspace byte offsets
#define OFF_WPACK 0UL                          // 128*20*64*16 = 2,621,440
#define OFF_XBF   2621440UL                    // 1024*64*128*2 = 16,777,216
#define OFF_EXCHA 19398656UL                   // agent region: 4*2*4096*8 = 262,144
#define OFF_EXCHL 19660800UL                   // local region: 4*2*4096*8 = 262,144
#define OFF_V     19922944UL                   // 512*4
#define OFF_C0S   19924992UL                   // 16
#define OFF_CTL   19925056UL                   // u32[16]: claim[0..3], spill=8, arrive=9
#define OFF_YPART 19925504UL                   // 1024*4*32*16*4 = 8,388,608

__device__ __forceinline__ ushort_t f2bf(float f){
    union { float f; unsigned u; } v; v.f = f;
    unsigned u = v.u;
    unsigned r = (u + 0x7fffu + ((u >> 16) & 1u)) >> 16;
    return (ushort_t)r;
}
__device__ __forceinline__ float sigm(float x){ return 1.f / (1.f + __expf(-x)); }
__device__ __forceinline__ float tanh_(float x){ float e = __expf(2.f * x); return (e - 1.f) / (e + 1.f); }

// ---- prep: pack W into MFMA A-operand fragments (bf16) ----------------------
__global__ void pack_weights(const float* __restrict__ Wxi, const float* __restrict__ Whi,
                             const float* __restrict__ Wxf, const float* __restrict__ Whf,
                             const float* __restrict__ Wxo, const float* __restrict__ Who,
                             const float* __restrict__ Wxc, const float* __restrict__ Whc,
                             ushort_t* __restrict__ wpack){
    int bid = blockIdx.x;            // = q*20 + ks
    int q = bid / 20, ks = bid % 20;
    int l = threadIdx.x;             // 0..63
    int m = l & 15, quad = l >> 4;
    int h = q * 4 + (m >> 2), g = m & 3;
    const float* Wh = (g == 0) ? Whi : (g == 1) ? Whf : (g == 2) ? Who : Whc;
    const float* Wx = (g == 0) ? Wxi : (g == 1) ? Wxf : (g == 2) ? Wxo : Wxc;
    union { ushort_t u[8]; uint4 v4; } tmp;
    #pragma unroll
    for (int j = 0; j < 8; j++){
        int k = ks * 32 + quad * 8 + j;
        float w = (k < NH) ? Wh[(size_t)k * NH + h] : Wx[(size_t)(k - NH) * NH + h];
        tmp.u[j] = f2bf(w);
    }
    *(uint4*)(wpack + ((size_t)bid * 64 + l) * 8) = tmp.v4;
}

// ---- prep: bf16 embeddings, layout [s][b][e] --------------------------------
__global__ void prep_x(const int* __restrict__ inputs, const float* __restrict__ emb,
                       ushort_t* __restrict__ xbf){
    unsigned tid = blockIdx.x * 256u + threadIdx.x;   // = (s*64+b)*128 + e
    unsigned e = tid & 127u;
    unsigned b = (tid >> 7) & 63u;
    unsigned s = tid >> 13;
    int row = inputs[(size_t)b * S_LEN + s];
    xbf[tid] = f2bf(emb[(size_t)row * NE + e]);
}

// ---- prep: v, c0, both exch regions (H0, tag 0), ctl = 0 --------------------
__global__ void prep_v(const float* __restrict__ Whq, const float* __restrict__ bq,
                       const float* __restrict__ dw, const float* __restrict__ db,
                       const float* __restrict__ H0, float* __restrict__ v,
                       float* __restrict__ c0, u64* __restrict__ exchA,
                       u64* __restrict__ exchL, unsigned* __restrict__ ctl){
    int t = threadIdx.x;   // 512 threads, 1 block
    float a = 0.f;
    for (int e = 0; e < NE; e++) a += Whq[(size_t)t * NE + e] * dw[e];
    v[t] = a;
    if (t == 0){
        float c = db[0];
        for (int e = 0; e < NE; e++) c += bq[e] * dw[e];
        *c0 = c;
    }
    if (t < 16) ctl[t] = 0;
    // agent region: [grp][parity][16 b_local][256 pair]; local region:
    // [grp][parity][256 pair(tid)][16 b_local] (consumer-thread contiguous)
    int p = t & 255, half = t >> 8;
    for (int b = half * 32; b < half * 32 + 32; b++){
        unsigned lo = (unsigned)f2bf(H0[(size_t)b * NH + 2 * p]) |
                      ((unsigned)f2bf(H0[(size_t)b * NH + 2 * p + 1]) << 16);
        exchA[(size_t)(b >> 4) * 8192 + (size_t)(b & 15) * 256 + p] = (u64)lo;  // tag=0
        exchL[(size_t)(b >> 4) * 8192 + (size_t)p * 16 + (b & 15)]  = (u64)lo;  // tag=0
    }
}

// ---- final: Y[s,b] = c0 + sum_wgin ypart[s][grp(b)][wgin][b&15] -------------
__global__ void reduce_y(const float* __restrict__ ypart, const float* __restrict__ c0,
                         float* __restrict__ dout){
    int t = blockIdx.x * 256 + threadIdx.x;   // t = s*64 + b, 65536 total
    int s = t >> 6, b = t & 63;
    int g = b >> 4, bl = b & 15;
    float a = *c0;
    const float* base = ypart + (((size_t)s * NGRP + g) * NWPG) * 16 + bl;
    #pragma unroll 4
    for (int w = 0; w < NWPG; w++) a += base[w * 16];
    dout[t] = a;
}

// ---- the recurrence ---------------------------------------------------------
__launch_bounds__(256, 1)
__global__ void lstm_coop(const float* __restrict__ C0,
                          const float* __restrict__ b_i, const float* __restrict__ b_f,
                          const float* __restrict__ b_o, const float* __restrict__ b_c,
                          const ushort_t* __restrict__ wpack, const ushort_t* __restrict__ xbf,
                          u64* __restrict__ exchA, u64* __restrict__ exchL,
                          unsigned* __restrict__ ctl, const float* __restrict__ v,
                          float* __restrict__ ypart, float* __restrict__ dout){
    __shared__ uint4 Hs[2][16][65];   // +pad: dword stride 260, conflict-free
    __shared__ uint4 Xs[3][16][17];
    __shared__ float yred[2][4][16];
    __shared__ int role[3];           // [group, wgin, local?]

    const int tid  = threadIdx.x;
    const int lane = tid & 63;
    const int wv   = tid >> 6;

    // ---- role discovery: claim slot in group = own XCD; spill fills deficits -
    if (tid == 0){
        unsigned x;
        asm volatile("s_getreg_b32 %0, hwreg(HW_REG_XCC_ID)" : "=s"(x));
        x &= 7u;
        unsigned ord = 0xFFFFFFFFu;
        if (x < NGRP)
            ord = __hip_atomic_fetch_add(&ctl[x], 1u, __ATOMIC_RELAXED,
                                         __HIP_MEMORY_SCOPE_AGENT);
        // one-time grid barrier (cooperative launch => all 256 WGs resident)
        __hip_atomic_fetch_add(&ctl[9], 1u, __ATOMIC_RELEASE, __HIP_MEMORY_SCOPE_AGENT);
        while (__hip_atomic_load(&ctl[9], __ATOMIC_ACQUIRE, __HIP_MEMORY_SCOPE_AGENT) < NWGT)
            __builtin_amdgcn_s_sleep(2);
        unsigned cl[NGRP];
        #pragma unroll
        for (int i = 0; i < NGRP; i++)
            cl[i] = __hip_atomic_load(&ctl[i], __ATOMIC_RELAXED, __HIP_MEMORY_SCOPE_AGENT);
        int gg = -1, ww = 0, loc = 0;
        if (x < NGRP && ord < NWPG){
            gg = (int)x; ww = (int)ord; loc = (cl[x] >= NWPG) ? 1 : 0;
        } else {
            unsigned sp = __hip_atomic_fetch_add(&ctl[8], 1u, __ATOMIC_RELAXED,
                                                 __HIP_MEMORY_SCOPE_AGENT);
            unsigned cum = 0;
            #pragma unroll
            for (int i = 0; i < NGRP; i++){
                unsigned fill = cl[i] < NWPG ? cl[i] : NWPG;
                unsigned def = NWPG - fill;
                if (gg < 0 && sp < cum + def){ gg = i; ww = (int)(fill + (sp - cum)); }
                cum += def;
            }
            loc = 0;
        }
        role[0] = gg; role[1] = ww; role[2] = loc;
    }
    __syncthreads();
    const int g    = role[0];
    const int wgin = role[1];
    int modeL      = role[2];          // sticky per-thread; may drop to 0
    if (g < 0) return;                 // unassigned WG: idle

    const int q    = wgin * 4 + wv;    // h-slot 0..127
    const int quad = lane >> 4;
    const int col  = lane & 15;
    const int h    = q * 4 + quad;
    const int b    = g * 16 + col;

    // persistent weights: 20 A-fragments (K=640)
    bf16x8 wfrag[20];
    #pragma unroll
    for (int ks = 0; ks < 20; ks++)
        wfrag[ks] = *(const bf16x8*)(wpack + ((size_t)(q * 20 + ks) * 64 + lane) * 8);

    const float bias0 = b_i[h], bias1 = b_f[h], bias2 = b_o[h], bias3 = b_c[h];
    const float vv = v[h];
    float C = C0[(size_t)b * NH + h];

    const u64* exgA = exchA + (size_t)g * 8192;
    u64*       ewgA = exchA + (size_t)g * 8192;
    u64*       exgL = exchL + (size_t)g * 8192;

    const char* HsB = (const char*)Hs;
    const char* XsB = (const char*)Xs;
    unsigned* HsD = (unsigned*)Hs;

    // preload x tile for s=0 into Xs[0]
    {
        const uint4* x0 = (const uint4*)(xbf + (size_t)(g * 16) * NE);
        Xs[0][tid >> 4][tid & 15] = x0[tid];
    }
    __syncthreads();

    for (int s = 0; s < S_LEN; s++){
        // x prefetch for s+1
        int sn = (s + 1 < S_LEN) ? s + 1 : s;
        uint4 xr = ((const uint4*)(xbf + ((size_t)sn * NB + g * 16) * NE))[tid];

        // ---- x-part MFMAs (Xs[s%3] synced at step s-1) -----------------------
        f32x4 acc0 = (f32x4){0.f, 0.f, 0.f, 0.f};
        f32x4 acc1 = (f32x4){0.f, 0.f, 0.f, 0.f};
        #pragma unroll
        for (int kx = 0; kx < 4; kx++){
            bf16x8 bfr = *(const bf16x8*)(XsB + (s % 3) * 4352 + col * 272 + kx * 64 + quad * 16);
            if (kx & 1) acc1 = __builtin_amdgcn_mfma_f32_16x16x32_bf16(wfrag[16 + kx], bfr, acc1, 0, 0, 0);
            else        acc0 = __builtin_amdgcn_mfma_f32_16x16x32_bf16(wfrag[16 + kx], bfr, acc0, 0, 0, 0);
        }

        // ---- poll H(s) -------------------------------------------------------
        const unsigned tag = (unsigned)s;
        const u64* exA = exgA + (size_t)(s & 1) * 4096;
        const u64* exL = exgL + (size_t)(s & 1) * 4096 + (size_t)tid * 16;
        unsigned d[16];
        int rounds = 0;
        for (;;){
            unsigned bad = 0;
            if (modeL){
                // one asm block: 8x dwordx4 sc0 (L1-bypass, XCD-L2 served)
                // + vmcnt(0) INSIDE => outputs valid at block end, no hazard.
                u32x4 o0, o1, o2, o3, o4, o5, o6, o7;
                asm volatile(
                    "global_load_dwordx4 %0, %8, off sc0\n\t"
                    "global_load_dwordx4 %1, %8, off offset:16 sc0\n\t"
                    "global_load_dwordx4 %2, %8, off offset:32 sc0\n\t"
                    "global_load_dwordx4 %3, %8, off offset:48 sc0\n\t"
                    "global_load_dwordx4 %4, %8, off offset:64 sc0\n\t"
                    "global_load_dwordx4 %5, %8, off offset:80 sc0\n\t"
                    "global_load_dwordx4 %6, %8, off offset:96 sc0\n\t"
                    "global_load_dwordx4 %7, %8, off offset:112 sc0\n\t"
                    "s_waitcnt vmcnt(0)"
                    : "=&v"(o0), "=&v"(o1), "=&v"(o2), "=&v"(o3),
                      "=&v"(o4), "=&v"(o5), "=&v"(o6), "=&v"(o7)
                    : "v"(exL));
                bad = (o0[1]^tag)|(o0[3]^tag)|(o1[1]^tag)|(o1[3]^tag)
                    | (o2[1]^tag)|(o2[3]^tag)|(o3[1]^tag)|(o3[3]^tag)
                    | (o4[1]^tag)|(o4[3]^tag)|(o5[1]^tag)|(o5[3]^tag)
                    | (o6[1]^tag)|(o6[3]^tag)|(o7[1]^tag)|(o7[3]^tag);
                d[0]=o0[0];  d[1]=o0[2];  d[2]=o1[0];  d[3]=o1[2];
                d[4]=o2[0];  d[5]=o2[2];  d[6]=o3[0];  d[7]=o3[2];
                d[8]=o4[0];  d[9]=o4[2];  d[10]=o5[0]; d[11]=o5[2];
                d[12]=o6[0]; d[13]=o6[2]; d[14]=o7[0]; d[15]=o7[2];
            } else {
                #pragma unroll
                for (int j = 0; j < 16; j++){
                    u64 w = __hip_atomic_load(exA + (size_t)j * 256 + tid,
                                              __ATOMIC_RELAXED, __HIP_MEMORY_SCOPE_AGENT);
                    bad |= ((unsigned)(w >> 32)) ^ tag;
                    d[j] = (unsigned)w;
                }
            }
            if (!bad) break;
            if (++rounds > 8192) modeL = 0;   // sticky fallback: no hang possible
            __builtin_amdgcn_s_sleep(1);
        }
        #pragma unroll
        for (int j = 0; j < 16; j++)
            HsD[(s & 1) * 4160 + j * 260 + tid] = d[j];   // row j, dword tid
        Xs[(s + 1) % 3][tid >> 4][tid & 15] = xr;
        __syncthreads();   // the only in-loop barrier: Hs[s&1] + Xs ready

        // ---- flush previous step's Y partials (reuses this barrier) ----------
        if (tid < 16 && s > 0)
            ypart[(((size_t)(s - 1) * NGRP + g) * NWPG + wgin) * 16 + tid] =
                yred[(s - 1) & 1][0][tid] + yred[(s - 1) & 1][1][tid] +
                yred[(s - 1) & 1][2][tid] + yred[(s - 1) & 1][3][tid];

        // ---- H-part: 16 MFMA from LDS (2-way split accumulator) --------------
        #pragma unroll
        for (int ks = 0; ks < 16; ks++){
            bf16x8 bfr = *(const bf16x8*)(HsB + (s & 1) * 16640 + col * 1040 + ks * 64 + quad * 16);
            if (ks & 1) acc1 = __builtin_amdgcn_mfma_f32_16x16x32_bf16(wfrag[ks], bfr, acc1, 0, 0, 0);
            else        acc0 = __builtin_amdgcn_mfma_f32_16x16x32_bf16(wfrag[ks], bfr, acc0, 0, 0, 0);
        }
        f32x4 acc = acc0 + acc1;

        // ---- cell update: acc regs = {i,f,o,c} for (b, h) ---------------------
        float I = sigm(acc[0] + bias0);
        float F = sigm(acc[1] + bias1);
        float O = sigm(acc[2] + bias2);
        float G = tanh_(acc[3] + bias3);
        float Cn = F * C + I * G;
        float Hn = O * tanh_(Cn);
        C = Cn;

        // ---- publish H(s+1): dual (local L2 + agent), fire-and-forget ---------
        float Hn_hi = __shfl_xor(Hn, 16, 64);
        {
            unsigned lo = (unsigned)f2bf(Hn) | ((unsigned)f2bf(Hn_hi) << 16);
            if ((quad & 1) == 0 && s < S_LEN - 1){
                u64 word = ((u64)(unsigned)(s + 1) << 32) | (u64)lo;
                unsigned pidx = (unsigned)(q * 2) + (unsigned)(quad >> 1);
                __hip_atomic_store(ewgA + (size_t)((s + 1) & 1) * 4096 +
                                   (size_t)col * 256 + pidx, word,
                                   __ATOMIC_RELAXED, __HIP_MEMORY_SCOPE_AGENT);
                exgL[(size_t)((s + 1) & 1) * 4096 + (size_t)pidx * 16 + col] = word;
            }
        }

        // ---- Y partial into LDS (read after NEXT step's barrier) -------------
        float p = Hn * vv;
        p += __shfl_xor(p, 16, 64);
        p += __shfl_xor(p, 32, 64);
        if (quad == 0) yred[s & 1][wv][col] = p;

        if (s == S_LEN - 1){
            dout[65536 + (size_t)b * NH + h] = Hn;   // final H
            dout[98304 + (size_t)b * NH + h] = Cn;   // final C
        }
    }
    // final Y flush for s = S_LEN-1
    __syncthreads();
    if (tid < 16)
        ypart[(((size_t)(S_LEN - 1) * NGRP + g) * NWPG + wgin) * 16 + tid] =
            yred[(S_LEN - 1) & 1][0][tid] + yred[(S_LEN - 1) & 1][1][tid] +
            yred[(S_LEN - 1) & 1][2][tid] + yred[(S_LEN - 1) & 1][3][tid];
}

extern "C" void kernel_launch(void* const* d_in, const int* in_sizes, int n_in,
                              void* d_out, int out_size, void* d_ws, size_t ws_size,
                              hipStream_t stream){
    const int*   inputs = (const int*)  d_in[0];
    const float* H0     = (const float*)d_in[1];
    const float* C0     = (const float*)d_in[2];
    const float* emb    = (const float*)d_in[3];
    const float* W_xi   = (const float*)d_in[4];
    const float* W_hi   = (const float*)d_in[5];
    const float* b_i    = (const float*)d_in[6];
    const float* W_xf   = (const float*)d_in[7];
    const float* W_hf   = (const float*)d_in[8];
    const float* b_f    = (const float*)d_in[9];
    const float* W_xo   = (const float*)d_in[10];
    const float* W_ho   = (const float*)d_in[11];
    const float* b_o    = (const float*)d_in[12];
    const float* W_xc   = (const float*)d_in[13];
    const float* W_hc   = (const float*)d_in[14];
    const float* b_c    = (const float*)d_in[15];
    const float* W_hq   = (const float*)d_in[16];
    const float* b_q    = (const float*)d_in[17];
    const float* dw     = (const float*)d_in[18];
    const float* db     = (const float*)d_in[19];
    float* dout = (float*)d_out;

    char* ws = (char*)d_ws;
    ushort_t* wpack = (ushort_t*)(ws + OFF_WPACK);
    ushort_t* xbf   = (ushort_t*)(ws + OFF_XBF);
    u64*      exchA = (u64*)     (ws + OFF_EXCHA);
    u64*      exchL = (u64*)     (ws + OFF_EXCHL);
    float*    v     = (float*)   (ws + OFF_V);
    float*    c0    = (float*)   (ws + OFF_C0S);
    unsigned* ctl   = (unsigned*)(ws + OFF_CTL);
    float*    ypart = (float*)   (ws + OFF_YPART);

    pack_weights<<<dim3(128 * 20), dim3(64), 0, stream>>>(W_xi, W_hi, W_xf, W_hf,
                                                          W_xo, W_ho, W_xc, W_hc, wpack);
    prep_x<<<dim3((S_LEN * NB * NE) / 256), dim3(256), 0, stream>>>(inputs, emb, xbf);
    prep_v<<<dim3(1), dim3(512), 0, stream>>>(W_hq, b_q, dw, db, H0, v, c0,
                                              exchA, exchL, ctl);

    void* args[] = { (void*)&C0, (void*)&b_i, (void*)&b_f, (void*)&b_o, (void*)&b_c,
                     (void*)&wpack, (void*)&xbf, (void*)&exchA, (void*)&exchL,
                     (void*)&ctl, (void*)&v, (void*)&ypart, (void*)&dout };
    hipLaunchCooperativeKernel((void*)lstm_coop, dim3(NWGT), dim3(256), args, 0, stream);

    reduce_y<<<dim3(65536 / 256), dim3(256), 0, stream>>>(ypart, c0, dout);
}

// Round 6
// 3109.338 us; speedup vs baseline: 25.3415x; 25.3415x over previous
//
#include <hip/hip_runtime.h>

// LSTM LM forward on gfx950.
// R16 = R10 (proven 2941-3123us: 128 WGs, 4 groups x 32 WGs x 16 batches,
// 1 h-slot/wave, wfrag[20]) + ONE delta: sentinel-based resweep.
// Session evidence: R11 (stagger: algebra error, 8.6ms), R12 (ready-counter
// trails data, 7.7ms), R13 (1024-thr consolidation: LDS service x4, 4.2ms),
// R15 (XCD-local sc0 exchange: store->sc0-load visibility ~1e5 cyc, 79ms).
// Surviving derived fact: each consumer thread's 16 exchange words
// (j*256+tid) are all written by ONE instruction of ONE producer wave
// (h-slot q=tid>>1 covers all 16 b_locals x 2 pairs in its 32 active lanes),
// so ONE sentinel word detects readiness of all 16. Resweep now spins on
// ex[tid] only (8B/thr/round; 256KB/round machine-wide vs R10's 4MB), then
// reloads all 16 once. Outer verify-all loop kept as correctness fallback;
// first poll (16 loads issued early, x-MFMAs overlap) unchanged -> behavior
// identical to R10 when data is already present.
// Carried from R10: tagged u64 {step, 2xbf16} H exchange via relaxed
// AGENT-scope atomics, Hs parity dbuf + Xs triple-buf, one barrier/step,
// deferred Y flush via yred parity LDS + reduce_y, 2-way split accumulator,
// folded head Y = H.v + c0.

typedef short bf16x8 __attribute__((ext_vector_type(8)));
typedef float f32x4  __attribute__((ext_vector_type(4)));
typedef unsigned short ushort_t;
typedef unsigned long long u64;

#define S_LEN 1024
#define NB    64
#define NH    512
#define NE    128
#define NGRP  4
#define NWPG  32              // WGs per group
#define NWGT  128             // total WGs

// workspace byte offsets
#define OFF_WPACK 0UL                          // 128*20*64*16 = 2,621,440
#define OFF_XBF   2621440UL                    // 1024*64*128*2 = 16,777,216
#define OFF_EXCH  19398656UL                   // 4 grp * 2 par * 4096 u64 * 8 = 262,144
#define OFF_V     19660800UL                   // 512*4
#define OFF_C0S   19662848UL                   // 16
#define OFF_YPART 19663360UL                   // 1024*4*32*16*4 = 8,388,608

__device__ __forceinline__ ushort_t f2bf(float f){
    union { float f; unsigned u; } v; v.f = f;
    unsigned u = v.u;
    unsigned r = (u + 0x7fffu + ((u >> 16) & 1u)) >> 16;
    return (ushort_t)r;
}
__device__ __forceinline__ float sigm(float x){ return 1.f / (1.f + __expf(-x)); }
__device__ __forceinline__ float tanh_(float x){ float e = __expf(2.f * x); return (e - 1.f) / (e + 1.f); }

// ---- prep: pack W into MFMA A-operand fragments (bf16) ----------------------
// wpack[q][ks][lane][j]: A[m=lane&15][k=32*ks+(lane>>4)*8+j]; m -> h=4q+(m>>2),
// gate g=m&3; k<512: W_h[g][k][h]; k>=512: W_x[g][k-512][h]
__global__ void pack_weights(const float* __restrict__ Wxi, const float* __restrict__ Whi,
                             const float* __restrict__ Wxf, const float* __restrict__ Whf,
                             const float* __restrict__ Wxo, const float* __restrict__ Who,
                             const float* __restrict__ Wxc, const float* __restrict__ Whc,
                             ushort_t* __restrict__ wpack){
    int bid = blockIdx.x;            // = q*20 + ks
    int q = bid / 20, ks = bid % 20;
    int l = threadIdx.x;             // 0..63
    int m = l & 15, quad = l >> 4;
    int h = q * 4 + (m >> 2), g = m & 3;
    const float* Wh = (g == 0) ? Whi : (g == 1) ? Whf : (g == 2) ? Who : Whc;
    const float* Wx = (g == 0) ? Wxi : (g == 1) ? Wxf : (g == 2) ? Wxo : Wxc;
    union { ushort_t u[8]; uint4 v4; } tmp;
    #pragma unroll
    for (int j = 0; j < 8; j++){
        int k = ks * 32 + quad * 8 + j;
        float w = (k < NH) ? Wh[(size_t)k * NH + h] : Wx[(size_t)(k - NH) * NH + h];
        tmp.u[j] = f2bf(w);
    }
    *(uint4*)(wpack + ((size_t)bid * 64 + l) * 8) = tmp.v4;
}

// ---- prep: bf16 embeddings, layout [s][b][e] --------------------------------
__global__ void prep_x(const int* __restrict__ inputs, const float* __restrict__ emb,
                       ushort_t* __restrict__ xbf){
    unsigned tid = blockIdx.x * 256u + threadIdx.x;   // = (s*64+b)*128 + e
    unsigned e = tid & 127u;
    unsigned b = (tid >> 7) & 63u;
    unsigned s = tid >> 13;
    int row = inputs[(size_t)b * S_LEN + s];
    xbf[tid] = f2bf(emb[(size_t)row * NE + e]);
}

// ---- prep: v = W_hq @ dense_w, c0, exch init (H0, tag 0, parity 0) ----------
__global__ void prep_v(const float* __restrict__ Whq, const float* __restrict__ bq,
                       const float* __restrict__ dw, const float* __restrict__ db,
                       const float* __restrict__ H0, float* __restrict__ v,
                       float* __restrict__ c0, u64* __restrict__ exch){
    int t = threadIdx.x;   // 512 threads, 1 block
    float a = 0.f;
    for (int e = 0; e < NE; e++) a += Whq[(size_t)t * NE + e] * dw[e];
    v[t] = a;
    if (t == 0){
        float c = db[0];
        for (int e = 0; e < NE; e++) c += bq[e] * dw[e];
        *c0 = c;
    }
    // exch layout: [grp][parity][16 b_local][256 hpair] of u64 {tag, data}
    int p = t & 255, half = t >> 8;
    for (int b = half * 32; b < half * 32 + 32; b++){
        unsigned lo = (unsigned)f2bf(H0[(size_t)b * NH + 2 * p]) |
                      ((unsigned)f2bf(H0[(size_t)b * NH + 2 * p + 1]) << 16);
        exch[(size_t)(b >> 4) * 8192 + (size_t)(b & 15) * 256 + p] = (u64)lo;  // tag=0
    }
}

// ---- final: Y[s,b] = c0 + sum_wgin ypart[s][grp(b)][wgin][b&15] -------------
__global__ void reduce_y(const float* __restrict__ ypart, const float* __restrict__ c0,
                         float* __restrict__ dout){
    int t = blockIdx.x * 256 + threadIdx.x;   // t = s*64 + b, 65536 total
    int s = t >> 6, b = t & 63;
    int g = b >> 4, bl = b & 15;
    float a = *c0;
    const float* base = ypart + (((size_t)s * NGRP + g) * NWPG) * 16 + bl;
    #pragma unroll 4
    for (int w = 0; w < NWPG; w++) a += base[w * 16];
    dout[t] = a;
}

// ---- the recurrence ---------------------------------------------------------
__launch_bounds__(256, 1)
__global__ void lstm_coop(const float* __restrict__ C0,
                          const float* __restrict__ b_i, const float* __restrict__ b_f,
                          const float* __restrict__ b_o, const float* __restrict__ b_c,
                          const ushort_t* __restrict__ wpack, const ushort_t* __restrict__ xbf,
                          u64* __restrict__ exch, const float* __restrict__ v,
                          float* __restrict__ ypart, float* __restrict__ dout){
    // LDS: Hs double-buffered [2][16 rows][65 uint4] (+pad -> dword stride 260,
    // conflict-free staging), Xs triple-buffered [3][16][17] uint4,
    // yred parity-double-buffered wave partials.
    __shared__ uint4 Hs[2][16][65];
    __shared__ uint4 Xs[3][16][17];
    __shared__ float yred[2][4][16];

    const int tid  = threadIdx.x;
    const int lane = tid & 63;
    const int wv   = tid >> 6;
    const int wg   = blockIdx.x;
    const int g    = wg >> 5;              // batch group 0..3
    const int wgin = wg & 31;              // WG index within group
    const int q    = wgin * 4 + wv;        // h-slot 0..127
    const int quad = lane >> 4;
    const int col  = lane & 15;
    const int h    = q * 4 + quad;         // this lane's h column
    const int b    = g * 16 + col;         // this lane's batch

    // persistent weights: 20 A-fragments (K=640)
    bf16x8 wfrag[20];
    #pragma unroll
    for (int ks = 0; ks < 20; ks++)
        wfrag[ks] = *(const bf16x8*)(wpack + ((size_t)(q * 20 + ks) * 64 + lane) * 8);

    const float bias0 = b_i[h], bias1 = b_f[h], bias2 = b_o[h], bias3 = b_c[h];
    const float vv = v[h];
    float C = C0[(size_t)b * NH + h];

    u64* exg = exch + (size_t)g * 8192;    // this group's double buffer

    const char* HsB = (const char*)Hs;
    const char* XsB = (const char*)Xs;
    unsigned* HsD = (unsigned*)Hs;

    // preload x tile for s=0 into Xs[0]; barrier so early x-MFMAs at s=0 are safe
    {
        const uint4* x0 = (const uint4*)(xbf + (size_t)(g * 16) * NE);
        Xs[0][tid >> 4][tid & 15] = x0[tid];
    }
    __syncthreads();

    for (int s = 0; s < S_LEN; s++){
        // x prefetch for s+1 (lands during poll)
        int sn = (s + 1 < S_LEN) ? s + 1 : s;
        uint4 xr = ((const uint4*)(xbf + ((size_t)sn * NB + g * 16) * NE))[tid];

        // ---- issue poll loads for H(s) ---------------------------------------
        const u64* ex = exg + (size_t)(s & 1) * 4096;
        const unsigned tag = (unsigned)s;
        u64 hv[16];
        #pragma unroll
        for (int j = 0; j < 16; j++)
            hv[j] = __hip_atomic_load(ex + (size_t)j * 256 + tid, __ATOMIC_RELAXED,
                                      __HIP_MEMORY_SCOPE_AGENT);

        // ---- x-part MFMAs overlap the poll (Xs[s%3] synced at step s-1) ------
        f32x4 acc0 = (f32x4){0.f, 0.f, 0.f, 0.f};
        f32x4 acc1 = (f32x4){0.f, 0.f, 0.f, 0.f};
        #pragma unroll
        for (int kx = 0; kx < 4; kx++){
            bf16x8 bfr = *(const bf16x8*)(XsB + (s % 3) * 4352 + col * 272 + kx * 64 + quad * 16);
            if (kx & 1) acc1 = __builtin_amdgcn_mfma_f32_16x16x32_bf16(wfrag[16 + kx], bfr, acc1, 0, 0, 0);
            else        acc0 = __builtin_amdgcn_mfma_f32_16x16x32_bf16(wfrag[16 + kx], bfr, acc0, 0, 0, 0);
        }

        // ---- finish poll: sentinel spin + reload (verify-all as fallback) ----
        // All 16 of this thread's words are written by ONE instruction of ONE
        // producer wave (h-slot q=tid>>1), so ex[tid]'s tag detects all 16.
        for (;;){
            unsigned bad = 0;
            #pragma unroll
            for (int j = 0; j < 16; j++)
                bad |= ((unsigned)(hv[j] >> 32) != tag) ? 1u : 0u;
            if (!bad) break;
            u64 w0;
            do {
                __builtin_amdgcn_s_sleep(1);
                w0 = __hip_atomic_load(ex + tid, __ATOMIC_RELAXED,
                                       __HIP_MEMORY_SCOPE_AGENT);
            } while ((unsigned)(w0 >> 32) != tag);
            hv[0] = w0;
            #pragma unroll
            for (int j = 1; j < 16; j++)
                hv[j] = __hip_atomic_load(ex + (size_t)j * 256 + tid, __ATOMIC_RELAXED,
                                          __HIP_MEMORY_SCOPE_AGENT);
        }
        #pragma unroll
        for (int j = 0; j < 16; j++)
            HsD[(s & 1) * 4160 + j * 260 + tid] = (unsigned)hv[j];  // row j, dword tid
        Xs[(s + 1) % 3][tid >> 4][tid & 15] = xr;
        __syncthreads();   // the only in-loop barrier: Hs[s&1] + Xs ready

        // ---- flush previous step's Y partials (reuses this barrier) ----------
        if (tid < 16 && s > 0)
            ypart[(((size_t)(s - 1) * NGRP + g) * NWPG + wgin) * 16 + tid] =
                yred[(s - 1) & 1][0][tid] + yred[(s - 1) & 1][1][tid] +
                yred[(s - 1) & 1][2][tid] + yred[(s - 1) & 1][3][tid];

        // ---- H-part: 16 MFMA from LDS (2-way split accumulator) --------------
        #pragma unroll
        for (int ks = 0; ks < 16; ks++){
            bf16x8 bfr = *(const bf16x8*)(HsB + (s & 1) * 16640 + col * 1040 + ks * 64 + quad * 16);
            if (ks & 1) acc1 = __builtin_amdgcn_mfma_f32_16x16x32_bf16(wfrag[ks], bfr, acc1, 0, 0, 0);
            else        acc0 = __builtin_amdgcn_mfma_f32_16x16x32_bf16(wfrag[ks], bfr, acc0, 0, 0, 0);
        }
        f32x4 acc = acc0 + acc1;

        // ---- cell update: acc regs = {i,f,o,c} for (b, h) ---------------------
        float I = sigm(acc[0] + bias0);
        float F = sigm(acc[1] + bias1);
        float O = sigm(acc[2] + bias2);
        float G = tanh_(acc[3] + bias3);
        float Cn = F * C + I * G;
        float Hn = O * tanh_(Cn);
        C = Cn;

        // ---- publish H(s+1): tagged u64, lane-pair packed, fire-and-forget ----
        float Hn_hi = __shfl_xor(Hn, 16, 64);         // partner quad's value
        {
            unsigned lo = (unsigned)f2bf(Hn) | ((unsigned)f2bf(Hn_hi) << 16);
            if ((quad & 1) == 0 && s < S_LEN - 1){
                u64* ew = exg + (size_t)((s + 1) & 1) * 4096;
                unsigned idx = (unsigned)col * 256 + (unsigned)(q * 2) + (unsigned)(quad >> 1);
                u64 word = ((u64)(unsigned)(s + 1) << 32) | (u64)lo;
                __hip_atomic_store(ew + idx, word, __ATOMIC_RELAXED,
                                   __HIP_MEMORY_SCOPE_AGENT);
            }
        }

        // ---- Y partial into LDS (read after NEXT step's barrier) -------------
        float p = Hn * vv;
        p += __shfl_xor(p, 16, 64);
        p += __shfl_xor(p, 32, 64);
        if (quad == 0) yred[s & 1][wv][col] = p;

        if (s == S_LEN - 1){
            dout[65536 + (size_t)b * NH + h] = Hn;   // final H
            dout[98304 + (size_t)b * NH + h] = Cn;   // final C
        }
    }
    // final Y flush for s = S_LEN-1
    __syncthreads();
    if (tid < 16)
        ypart[(((size_t)(S_LEN - 1) * NGRP + g) * NWPG + wgin) * 16 + tid] =
            yred[(S_LEN - 1) & 1][0][tid] + yred[(S_LEN - 1) & 1][1][tid] +
            yred[(S_LEN - 1) & 1][2][tid] + yred[(S_LEN - 1) & 1][3][tid];
}

extern "C" void kernel_launch(void* const* d_in, const int* in_sizes, int n_in,
                              void* d_out, int out_size, void* d_ws, size_t ws_size,
                              hipStream_t stream){
    const int*   inputs = (const int*)  d_in[0];
    const float* H0     = (const float*)d_in[1];
    const float* C0     = (const float*)d_in[2];
    const float* emb    = (const float*)d_in[3];
    const float* W_xi   = (const float*)d_in[4];
    const float* W_hi   = (const float*)d_in[5];
    const float* b_i    = (const float*)d_in[6];
    const float* W_xf   = (const float*)d_in[7];
    const float* W_hf   = (const float*)d_in[8];
    const float* b_f    = (const float*)d_in[9];
    const float* W_xo   = (const float*)d_in[10];
    const float* W_ho   = (const float*)d_in[11];
    const float* b_o    = (const float*)d_in[12];
    const float* W_xc   = (const float*)d_in[13];
    const float* W_hc   = (const float*)d_in[14];
    const float* b_c    = (const float*)d_in[15];
    const float* W_hq   = (const float*)d_in[16];
    const float* b_q    = (const float*)d_in[17];
    const float* dw     = (const float*)d_in[18];
    const float* db     = (const float*)d_in[19];
    float* dout = (float*)d_out;

    char* ws = (char*)d_ws;
    ushort_t* wpack = (ushort_t*)(ws + OFF_WPACK);
    ushort_t* xbf   = (ushort_t*)(ws + OFF_XBF);
    u64*      exch  = (u64*)     (ws + OFF_EXCH);
    float*    v     = (float*)   (ws + OFF_V);
    float*    c0    = (float*)   (ws + OFF_C0S);
    float*    ypart = (float*)   (ws + OFF_YPART);

    pack_weights<<<dim3(128 * 20), dim3(64), 0, stream>>>(W_xi, W_hi, W_xf, W_hf,
                                                          W_xo, W_ho, W_xc, W_hc, wpack);
    prep_x<<<dim3((S_LEN * NB * NE) / 256), dim3(256), 0, stream>>>(inputs, emb, xbf);
    prep_v<<<dim3(1), dim3(512), 0, stream>>>(W_hq, b_q, dw, db, H0, v, c0, exch);

    void* args[] = { (void*)&C0, (void*)&b_i, (void*)&b_f, (void*)&b_o, (void*)&b_c,
                     (void*)&wpack, (void*)&xbf, (void*)&exch, (void*)&v,
                     (void*)&ypart, (void*)&dout };
    hipLaunchCooperativeKernel((void*)lstm_coop, dim3(NWGT), dim3(256), args, 0, stream);

    reduce_y<<<dim3(65536 / 256), dim3(256), 0, stream>>>(ypart, c0, dout);
}